// Round 1
// baseline (537.869 us; speedup 1.0000x reference)
//
#include <hip/hip_runtime.h>
#include <hip/hip_fp16.h>
#include <stdint.h>

typedef _Float16 f16;
typedef _Float16 f16x4 __attribute__((ext_vector_type(4)));
typedef _Float16 f16x8 __attribute__((ext_vector_type(8)));
typedef float f32x4 __attribute__((ext_vector_type(4)));

__device__ __forceinline__ float fpq(float t) {
    float r = rintf(t * 256.0f);                      // round-half-even, matches jnp.round
    r = fminf(fmaxf(r, -32768.0f), 32767.0f);
    return r * 0.00390625f;                           // exact /256
}

// ---------------- LayerNorm: fp32 row (1024) -> fp16 row ----------------
__global__ __launch_bounds__(256) void ln_kernel(
        const float* __restrict__ x, const float* __restrict__ g,
        const float* __restrict__ b, f16* __restrict__ out) {
    int row = blockIdx.x;
    int t = threadIdx.x;
    const float4* xr = (const float4*)(x + (size_t)row * 1024);
    float4 v = xr[t];
    float s = v.x + v.y + v.z + v.w;
    float s2 = v.x * v.x + v.y * v.y + v.z * v.z + v.w * v.w;
#pragma unroll
    for (int o = 32; o >= 1; o >>= 1) {
        s += __shfl_down(s, o);
        s2 += __shfl_down(s2, o);
    }
    __shared__ float red[8];
    int wid = t >> 6;
    if ((t & 63) == 0) { red[wid] = s; red[4 + wid] = s2; }
    __syncthreads();
    float ts = red[0] + red[1] + red[2] + red[3];
    float ts2 = red[4] + red[5] + red[6] + red[7];
    float mu = ts * (1.0f / 1024.0f);
    float var = ts2 * (1.0f / 1024.0f) - mu * mu;
    float rs = rsqrtf(var + 1e-5f);
    float4 gg = ((const float4*)g)[t];
    float4 bb = ((const float4*)b)[t];
    f16x4 o4;
    o4[0] = (f16)((v.x - mu) * rs * gg.x + bb.x);
    o4[1] = (f16)((v.y - mu) * rs * gg.y + bb.y);
    o4[2] = (f16)((v.z - mu) * rs * gg.z + bb.z);
    o4[3] = (f16)((v.w - mu) * rs * gg.w + bb.w);
    ((f16x4*)out)[(size_t)row * 256 + t] = o4;
}

// ---------------- W [K,N] fp32 -> WT [N,K] fp16 ----------------
__global__ __launch_bounds__(256) void transpose_kernel(
        const float* __restrict__ W, f16* __restrict__ WT, int K, int N) {
    __shared__ float tile[32][33];
    int n0 = blockIdx.x * 32, k0 = blockIdx.y * 32;
    int tx = threadIdx.x & 31, ty = threadIdx.x >> 5;
#pragma unroll
    for (int i = 0; i < 32; i += 8)
        tile[ty + i][tx] = W[(size_t)(k0 + ty + i) * N + n0 + tx];
    __syncthreads();
#pragma unroll
    for (int i = 0; i < 32; i += 8)
        WT[(size_t)(n0 + ty + i) * K + k0 + tx] = (f16)tile[tx][ty + i];
}

// ---------------- GEMM: C[M,N] = A[M,K] * BT[N,K]^T, fp16 in, fused epilogues ----
// EPI 0: +bias, fpq, scatter to q/k/v [B,H,S,64] fp16
// EPI 1: +bias, fpq, + resid(x), fpq -> fp32 out (N=1024)
// EPI 2: +bias, fpq, relu -> fp16 out [M,N]
// EPI 3: same as 1 (resid = x1, out = d_out)
template <int EPI>
__global__ __launch_bounds__(256) void gemm_kernel(
        const f16* __restrict__ A, const f16* __restrict__ BT,
        int N, int K,
        const float* __restrict__ bias, const float* __restrict__ resid,
        void* __restrict__ out0, f16* __restrict__ outk, f16* __restrict__ outv) {
    __shared__ f16 As[128 * 32];
    __shared__ f16 Bs[128 * 32];
    int m0 = blockIdx.x * 128, n0 = blockIdx.y * 128;
    int t = threadIdx.x;
    int lane = t & 63, w = t >> 6;
    int wm = w >> 1, wn = w & 1;
    int lr = lane & 15, lg = lane >> 4;
    f32x4 acc[4][4] = {};
    for (int k0 = 0; k0 < K; k0 += 32) {
        __syncthreads();
#pragma unroll
        for (int i = 0; i < 2; ++i) {
            int slot = i * 256 + t;
            int row = slot >> 2, c8 = (slot & 3) * 8;
            __builtin_amdgcn_global_load_lds(
                (const __attribute__((address_space(1))) uint32_t*)(A + (size_t)(m0 + row) * K + k0 + c8),
                (__attribute__((address_space(3))) uint32_t*)(As + slot * 8), 16, 0, 0);
            __builtin_amdgcn_global_load_lds(
                (const __attribute__((address_space(1))) uint32_t*)(BT + (size_t)(n0 + row) * K + k0 + c8),
                (__attribute__((address_space(3))) uint32_t*)(Bs + slot * 8), 16, 0, 0);
        }
        __syncthreads();
        f16x8 af[4], bf[4];
#pragma unroll
        for (int i = 0; i < 4; ++i)
            af[i] = *(const f16x8*)&As[(wm * 64 + i * 16 + lr) * 32 + lg * 8];
#pragma unroll
        for (int j = 0; j < 4; ++j)
            bf[j] = *(const f16x8*)&Bs[(wn * 64 + j * 16 + lr) * 32 + lg * 8];
#pragma unroll
        for (int i = 0; i < 4; ++i)
#pragma unroll
            for (int j = 0; j < 4; ++j)
                acc[i][j] = __builtin_amdgcn_mfma_f32_16x16x32_f16(af[i], bf[j], acc[i][j], 0, 0, 0);
    }
#pragma unroll
    for (int i = 0; i < 4; ++i) {
#pragma unroll
        for (int j = 0; j < 4; ++j) {
            int col = n0 + wn * 64 + j * 16 + lr;
            float bv = bias[col];
#pragma unroll
            for (int r = 0; r < 4; ++r) {
                int row = m0 + wm * 64 + i * 16 + lg * 4 + r;
                float val = acc[i][j][r] + bv;
                if (EPI == 0) {
                    float qv = fpq(val);
                    int part = col >> 10, wi = col & 1023;
                    int hd = wi >> 6, d = wi & 63;
                    int bb = row >> 10, ss = row & 1023;
                    f16* dst = part == 0 ? (f16*)out0 : (part == 1 ? outk : outv);
                    dst[((size_t)(bb * 16 + hd) * 1024 + ss) * 64 + d] = (f16)qv;
                } else if (EPI == 2) {
                    float hv = fmaxf(fpq(val), 0.0f);
                    ((f16*)out0)[(size_t)row * N + col] = (f16)hv;
                } else {
                    float o = fpq(resid[(size_t)row * 1024 + col] + fpq(val));
                    ((float*)out0)[(size_t)row * 1024 + col] = o;
                }
            }
        }
    }
}

// ---------------- Fused attention: two-pass (exact max/sum, then fpq(probs)·V) ----
// Q,K,V: [B*H, S=1024, 64] fp16 (exact fixed-point values). ctx: [B*S, 1024] fp16.
__global__ __launch_bounds__(256) void attn_kernel(
        const f16* __restrict__ Q, const f16* __restrict__ Kg,
        const f16* __restrict__ V, f16* __restrict__ ctx) {
    int qt = blockIdx.x, h = blockIdx.y, b = blockIdx.z;
    int bh = b * 16 + h;
    const f16* Qp = Q + ((size_t)bh * 1024 + qt * 64) * 64;
    const f16* Kp = Kg + (size_t)bh * 1024 * 64;
    const f16* Vp = V + (size_t)bh * 1024 * 64;
    int t = threadIdx.x, lane = t & 63, w = t >> 6;
    int lr = lane & 15, lg = lane >> 4;
    __shared__ f16 Ks[64][72];       // padded vs 16-way conflict at 128B stride
    __shared__ f16 Vt[64][72];       // transposed [d][k]
    __shared__ f16 Ps[4][16][72];    // wave-private P tiles
    f16x8 qf[2];
#pragma unroll
    for (int kk = 0; kk < 2; ++kk)
        qf[kk] = *(const f16x8*)(Qp + (w * 16 + lr) * 64 + kk * 32 + lg * 8);
    float m[4], l[4];
#pragma unroll
    for (int r = 0; r < 4; ++r) { m[r] = -1e30f; l[r] = 0.0f; }

    // ---- pass 1: running row max + sum(exp) ----
    for (int kt = 0; kt < 16; ++kt) {
        __syncthreads();
#pragma unroll
        for (int i = 0; i < 2; ++i) {
            int slot = i * 256 + t;
            int row = slot >> 3, c8 = (slot & 7) * 8;
            *(float4*)&Ks[row][c8] = *(const float4*)(Kp + (size_t)(kt * 64 + row) * 64 + c8);
        }
        __syncthreads();
        f32x4 sc[4] = {};
#pragma unroll
        for (int kk = 0; kk < 2; ++kk)
#pragma unroll
            for (int nf = 0; nf < 4; ++nf) {
                f16x8 kf = *(const f16x8*)&Ks[nf * 16 + lr][kk * 32 + lg * 8];
                sc[nf] = __builtin_amdgcn_mfma_f32_16x16x32_f16(qf[kk], kf, sc[nf], 0, 0, 0);
            }
#pragma unroll
        for (int r = 0; r < 4; ++r) {
            float tm = -1e30f;
#pragma unroll
            for (int nf = 0; nf < 4; ++nf) tm = fmaxf(tm, sc[nf][r] * 0.125f);
#pragma unroll
            for (int o = 1; o < 16; o <<= 1) tm = fmaxf(tm, __shfl_xor(tm, o));
            float mn = fmaxf(m[r], tm);
            float sum = 0.0f;
#pragma unroll
            for (int nf = 0; nf < 4; ++nf) sum += __expf(sc[nf][r] * 0.125f - mn);
#pragma unroll
            for (int o = 1; o < 16; o <<= 1) sum += __shfl_xor(sum, o);
            l[r] = l[r] * __expf(m[r] - mn) + sum;
            m[r] = mn;
        }
    }
    float rl[4];
#pragma unroll
    for (int r = 0; r < 4; ++r) rl[r] = 1.0f / l[r];

    // ---- pass 2: recompute scores, p = fpq(exp*rl), PV ----
    f32x4 co[4] = {};
    for (int kt = 0; kt < 16; ++kt) {
        __syncthreads();
#pragma unroll
        for (int i = 0; i < 2; ++i) {
            int slot = i * 256 + t;
            int row = slot >> 3, c8 = (slot & 7) * 8;
            *(float4*)&Ks[row][c8] = *(const float4*)(Kp + (size_t)(kt * 64 + row) * 64 + c8);
            float4 vv = *(const float4*)(Vp + (size_t)(kt * 64 + row) * 64 + c8);
            f16x8 tv = __builtin_bit_cast(f16x8, vv);
#pragma unroll
            for (int jj = 0; jj < 8; ++jj) Vt[c8 + jj][row] = tv[jj];
        }
        __syncthreads();
        f32x4 sc[4] = {};
#pragma unroll
        for (int kk = 0; kk < 2; ++kk)
#pragma unroll
            for (int nf = 0; nf < 4; ++nf) {
                f16x8 kf = *(const f16x8*)&Ks[nf * 16 + lr][kk * 32 + lg * 8];
                sc[nf] = __builtin_amdgcn_mfma_f32_16x16x32_f16(qf[kk], kf, sc[nf], 0, 0, 0);
            }
#pragma unroll
        for (int nf = 0; nf < 4; ++nf)
#pragma unroll
            for (int r = 0; r < 4; ++r) {
                float p = fpq(__expf(sc[nf][r] * 0.125f - m[r]) * rl[r]);
                Ps[w][lg * 4 + r][nf * 16 + lr] = (f16)p;
            }
        // wave-private P: in-wave lgkmcnt ordering suffices, no barrier
#pragma unroll
        for (int kk = 0; kk < 2; ++kk) {
            f16x8 pa = *(const f16x8*)&Ps[w][lr][kk * 32 + lg * 8];
#pragma unroll
            for (int nf = 0; nf < 4; ++nf) {
                f16x8 vb = *(const f16x8*)&Vt[nf * 16 + lr][kk * 32 + lg * 8];
                co[nf] = __builtin_amdgcn_mfma_f32_16x16x32_f16(pa, vb, co[nf], 0, 0, 0);
            }
        }
    }
#pragma unroll
    for (int nf = 0; nf < 4; ++nf)
#pragma unroll
        for (int r = 0; r < 4; ++r) {
            int ss = qt * 64 + w * 16 + lg * 4 + r;
            ctx[((size_t)b * 1024 + ss) * 1024 + h * 64 + nf * 16 + lr] = (f16)co[nf][r];
        }
}

extern "C" void kernel_launch(void* const* d_in, const int* in_sizes, int n_in,
                              void* d_out, int out_size, void* d_ws, size_t ws_size,
                              hipStream_t stream) {
    const float* x     = (const float*)d_in[0];
    const float* Wqkv  = (const float*)d_in[1];
    const float* bqkv  = (const float*)d_in[2];
    const float* Wout  = (const float*)d_in[3];
    const float* bout  = (const float*)d_in[4];
    const float* W1    = (const float*)d_in[5];
    const float* b1    = (const float*)d_in[6];
    const float* W2    = (const float*)d_in[7];
    const float* b2    = (const float*)d_in[8];
    const float* g1    = (const float*)d_in[9];
    const float* beta1 = (const float*)d_in[10];
    const float* g2    = (const float*)d_in[11];
    const float* beta2 = (const float*)d_in[12];

    char* ws = (char*)d_ws;
    const size_t MB = 1ull << 20;
    f16*  q_h   = (f16*)(ws);             // 16 MB
    f16*  k_h   = (f16*)(ws + 16 * MB);   // 16 MB
    f16*  v_h   = (f16*)(ws + 32 * MB);   // 16 MB
    f16*  ctx_h = (f16*)(ws + 48 * MB);   // 16 MB
    f16*  h_h   = (f16*)(ws);             // 64 MB, reuses q/k/v/ctx after attention path
    f16*  xn_h  = (f16*)(ws + 64 * MB);   // 16 MB (xn, later xn2)
    float* x1   = (float*)(ws + 80 * MB); // 32 MB
    f16*  wT    = (f16*)(ws + 112 * MB);  // 8 MB (transposed weight, reused per GEMM)

    // --- attention branch ---
    ln_kernel<<<8192, 256, 0, stream>>>(x, g1, beta1, xn_h);
    transpose_kernel<<<dim3(96, 32), 256, 0, stream>>>(Wqkv, wT, 1024, 3072);
    gemm_kernel<0><<<dim3(64, 24), 256, 0, stream>>>(xn_h, wT, 3072, 1024, bqkv, nullptr, q_h, k_h, v_h);
    attn_kernel<<<dim3(16, 16, 8), 256, 0, stream>>>(q_h, k_h, v_h, ctx_h);
    transpose_kernel<<<dim3(32, 32), 256, 0, stream>>>(Wout, wT, 1024, 1024);
    gemm_kernel<1><<<dim3(64, 8), 256, 0, stream>>>(ctx_h, wT, 1024, 1024, bout, x, x1, nullptr, nullptr);
    // --- MLP branch ---
    ln_kernel<<<8192, 256, 0, stream>>>(x1, g2, beta2, xn_h);
    transpose_kernel<<<dim3(128, 32), 256, 0, stream>>>(W1, wT, 1024, 4096);
    gemm_kernel<2><<<dim3(64, 32), 256, 0, stream>>>(xn_h, wT, 4096, 1024, b1, nullptr, h_h, nullptr, nullptr);
    transpose_kernel<<<dim3(32, 128), 256, 0, stream>>>(W2, wT, 4096, 1024);
    gemm_kernel<3><<<dim3(64, 8), 256, 0, stream>>>(h_h, wT, 1024, 4096, b2, x1, d_out, nullptr, nullptr);
}

// Round 2
// 445.249 us; speedup vs baseline: 1.2080x; 1.2080x over previous
//
#include <hip/hip_runtime.h>
#include <hip/hip_fp16.h>
#include <stdint.h>

typedef _Float16 f16;
typedef _Float16 f16x4 __attribute__((ext_vector_type(4)));
typedef _Float16 f16x8 __attribute__((ext_vector_type(8)));
typedef float f32x4 __attribute__((ext_vector_type(4)));

__device__ __forceinline__ float fpq(float t) {
    float r = rintf(t * 256.0f);                      // round-half-even, matches jnp.round
    r = fminf(fmaxf(r, -32768.0f), 32767.0f);
    return r * 0.00390625f;                           // exact /256
}

// ---------------- LayerNorm: fp32 row (1024) -> fp16 row ----------------
__global__ __launch_bounds__(256) void ln_kernel(
        const float* __restrict__ x, const float* __restrict__ g,
        const float* __restrict__ b, f16* __restrict__ out) {
    int row = blockIdx.x;
    int t = threadIdx.x;
    const float4* xr = (const float4*)(x + (size_t)row * 1024);
    float4 v = xr[t];
    float s = v.x + v.y + v.z + v.w;
    float s2 = v.x * v.x + v.y * v.y + v.z * v.z + v.w * v.w;
#pragma unroll
    for (int o = 32; o >= 1; o >>= 1) {
        s += __shfl_down(s, o);
        s2 += __shfl_down(s2, o);
    }
    __shared__ float red[8];
    int wid = t >> 6;
    if ((t & 63) == 0) { red[wid] = s; red[4 + wid] = s2; }
    __syncthreads();
    float ts = red[0] + red[1] + red[2] + red[3];
    float ts2 = red[4] + red[5] + red[6] + red[7];
    float mu = ts * (1.0f / 1024.0f);
    float var = ts2 * (1.0f / 1024.0f) - mu * mu;
    float rs = rsqrtf(var + 1e-5f);
    float4 gg = ((const float4*)g)[t];
    float4 bb = ((const float4*)b)[t];
    f16x4 o4;
    o4[0] = (f16)((v.x - mu) * rs * gg.x + bb.x);
    o4[1] = (f16)((v.y - mu) * rs * gg.y + bb.y);
    o4[2] = (f16)((v.z - mu) * rs * gg.z + bb.z);
    o4[3] = (f16)((v.w - mu) * rs * gg.w + bb.w);
    ((f16x4*)out)[(size_t)row * 256 + t] = o4;
}

// ---------------- W [K,N] fp32 -> WT [N,K] fp16 ----------------
__global__ __launch_bounds__(256) void transpose_kernel(
        const float* __restrict__ W, f16* __restrict__ WT, int K, int N) {
    __shared__ float tile[32][33];
    int n0 = blockIdx.x * 32, k0 = blockIdx.y * 32;
    int tx = threadIdx.x & 31, ty = threadIdx.x >> 5;
#pragma unroll
    for (int i = 0; i < 32; i += 8)
        tile[ty + i][tx] = W[(size_t)(k0 + ty + i) * N + n0 + tx];
    __syncthreads();
#pragma unroll
    for (int i = 0; i < 32; i += 8)
        WT[(size_t)(n0 + ty + i) * K + k0 + tx] = (f16)tile[tx][ty + i];
}

// ---------------- GEMM: C[M,N] = A[M,K] * BT[N,K]^T, fp16 in, fused epilogues ----
// EPI 0: +bias, fpq, scatter q (normal), k (tiled+swizzled), v (transposed+tiled+swizzled)
// EPI 1/3: +bias, fpq, + resid, fpq -> fp32 out (N=1024)
// EPI 2: +bias, fpq, relu -> fp16 out [M,N]
template <int EPI>
__global__ __launch_bounds__(256) void gemm_kernel(
        const f16* __restrict__ A, const f16* __restrict__ BT,
        int N, int K,
        const float* __restrict__ bias, const float* __restrict__ resid,
        void* __restrict__ out0, f16* __restrict__ outk, f16* __restrict__ outv) {
    __shared__ f16 As[128 * 32];
    __shared__ f16 Bs[128 * 32];
    int m0 = blockIdx.x * 128, n0 = blockIdx.y * 128;
    int t = threadIdx.x;
    int lane = t & 63, w = t >> 6;
    int wm = w >> 1, wn = w & 1;
    int lr = lane & 15, lg = lane >> 4;
    f32x4 acc[4][4] = {};
    for (int k0 = 0; k0 < K; k0 += 32) {
        __syncthreads();
#pragma unroll
        for (int i = 0; i < 2; ++i) {
            int slot = i * 256 + t;
            int row = slot >> 2, c8 = (slot & 3) * 8;
            __builtin_amdgcn_global_load_lds(
                (const __attribute__((address_space(1))) uint32_t*)(A + (size_t)(m0 + row) * K + k0 + c8),
                (__attribute__((address_space(3))) uint32_t*)(As + slot * 8), 16, 0, 0);
            __builtin_amdgcn_global_load_lds(
                (const __attribute__((address_space(1))) uint32_t*)(BT + (size_t)(n0 + row) * K + k0 + c8),
                (__attribute__((address_space(3))) uint32_t*)(Bs + slot * 8), 16, 0, 0);
        }
        __syncthreads();
        f16x8 af[4], bf[4];
#pragma unroll
        for (int i = 0; i < 4; ++i)
            af[i] = *(const f16x8*)&As[(wm * 64 + i * 16 + lr) * 32 + lg * 8];
#pragma unroll
        for (int j = 0; j < 4; ++j)
            bf[j] = *(const f16x8*)&Bs[(wn * 64 + j * 16 + lr) * 32 + lg * 8];
#pragma unroll
        for (int i = 0; i < 4; ++i)
#pragma unroll
            for (int j = 0; j < 4; ++j)
                acc[i][j] = __builtin_amdgcn_mfma_f32_16x16x32_f16(af[i], bf[j], acc[i][j], 0, 0, 0);
    }
#pragma unroll
    for (int i = 0; i < 4; ++i) {
#pragma unroll
        for (int j = 0; j < 4; ++j) {
            int col = n0 + wn * 64 + j * 16 + lr;
            float bv = bias[col];
#pragma unroll
            for (int r = 0; r < 4; ++r) {
                int row = m0 + wm * 64 + i * 16 + lg * 4 + r;
                float val = acc[i][j][r] + bv;
                if (EPI == 0) {
                    float qv = fpq(val);
                    int part = col >> 10, wi = col & 1023;
                    int hd = wi >> 6, d = wi & 63;
                    int bb = row >> 10, ss = row & 1023;
                    size_t bh = (size_t)(bb * 16 + hd);
                    if (part == 0) {
                        ((f16*)out0)[(bh * 1024 + ss) * 64 + d] = (f16)qv;
                    } else if (part == 1) {
                        // K: [bh][kt][srow 0..63][d ^ ((srow&7)<<3)]
                        outk[bh * 65536 + (ss >> 6) * 4096 + (ss & 63) * 64 + (d ^ ((ss & 7) << 3))] = (f16)qv;
                    } else {
                        // V^T: [bh][kt][d 0..63][(srow&63) ^ ((d&7)<<3)]
                        outv[bh * 65536 + (ss >> 6) * 4096 + d * 64 + ((ss & 63) ^ ((d & 7) << 3))] = (f16)qv;
                    }
                } else if (EPI == 2) {
                    float hv = fmaxf(fpq(val), 0.0f);
                    ((f16*)out0)[(size_t)row * N + col] = (f16)hv;
                } else {
                    float o = fpq(resid[(size_t)row * 1024 + col] + fpq(val));
                    ((float*)out0)[(size_t)row * 1024 + col] = o;
                }
            }
        }
    }
}

// ---------------- Fused attention, swapped-QK^T, conflict-free ----------------
// Q: [bh][s][64] fp16; Kg: swizzled-tiled; Vt: transposed swizzled-tiled.
// Two-pass exact softmax (fpq(probs) forbids online PV rescale).
__global__ __launch_bounds__(256) void attn_kernel(
        const f16* __restrict__ Q, const f16* __restrict__ Kg,
        const f16* __restrict__ Vt, f16* __restrict__ ctx) {
    int id = blockIdx.x;
    int qt = (id >> 3) & 15;
    int bh = (id >> 7) * 8 + (id & 7);   // same-bh blocks -> same XCD residue
    int b = bh >> 4, h = bh & 15;
    const f16* Qp = Q + ((size_t)bh * 1024 + (size_t)qt * 64) * 64;
    const f16* Kp = Kg + (size_t)bh * 65536;
    const f16* Vp = Vt + (size_t)bh * 65536;
    int t = threadIdx.x, lane = t & 63, w = t >> 6;
    int lr = lane & 15, lg = lane >> 4;
    __shared__ f16 Ks[4096];
    __shared__ f16 Vs[4096];

    // Q fragments (B operand: col=q=lr, k=lg*8+e), pre-scaled by 1/8 (exact in fp16)
    f16x8 qf[2];
#pragma unroll
    for (int kk = 0; kk < 2; ++kk) {
        qf[kk] = *(const f16x8*)(Qp + (w * 16 + lr) * 64 + kk * 32 + lg * 8);
#pragma unroll
        for (int j = 0; j < 8; ++j) qf[kk][j] = qf[kk][j] * (f16)0.125f;
    }
    // krow_map: permuted K-row feed so P->PV fragment needs only own + lane^32 data.
    // score at lane(lr=q,lg), sc[nf][r] corresponds to k = 32*(nf>>1) + 8*(lg^(2*(nf&1))) + 4*(nf&1) + r
    int koff[4][2], voff[4][2];
#pragma unroll
    for (int nf = 0; nf < 4; ++nf) {
        int rowv = 32 * (nf >> 1) + 8 * ((lr >> 2) ^ (2 * (nf & 1))) + 4 * (nf & 1) + (lr & 3);
#pragma unroll
        for (int kk = 0; kk < 2; ++kk)
            koff[nf][kk] = rowv * 64 + (((kk * 4 + lg) ^ (rowv & 7)) * 8);
    }
#pragma unroll
    for (int db = 0; db < 4; ++db) {
        int d = db * 16 + lr;
#pragma unroll
        for (int kk = 0; kk < 2; ++kk)
            voff[db][kk] = d * 64 + (((kk * 4 + lg) ^ (d & 7)) * 8);
    }

    float m = -1e30f, l = 0.0f;
    // ---- pass 1: exact row max + sum(exp) ----
    for (int kt = 0; kt < 16; ++kt) {
        __syncthreads();
#pragma unroll
        for (int i = 0; i < 2; ++i) {
            int slot = i * 256 + t;
            __builtin_amdgcn_global_load_lds(
                (const __attribute__((address_space(1))) uint32_t*)(Kp + kt * 4096 + slot * 8),
                (__attribute__((address_space(3))) uint32_t*)(Ks + slot * 8), 16, 0, 0);
        }
        __syncthreads();
        f32x4 sc[4] = {};
#pragma unroll
        for (int kk = 0; kk < 2; ++kk)
#pragma unroll
            for (int nf = 0; nf < 4; ++nf) {
                f16x8 kf = *(const f16x8*)&Ks[koff[nf][kk]];
                sc[nf] = __builtin_amdgcn_mfma_f32_16x16x32_f16(kf, qf[kk], sc[nf], 0, 0, 0);
            }
        float tm = -1e30f;
#pragma unroll
        for (int nf = 0; nf < 4; ++nf)
#pragma unroll
            for (int r = 0; r < 4; ++r) tm = fmaxf(tm, sc[nf][r]);
        tm = fmaxf(tm, __shfl_xor(tm, 16));
        tm = fmaxf(tm, __shfl_xor(tm, 32));
        float mn = fmaxf(m, tm);
        float sum = 0.0f;
#pragma unroll
        for (int nf = 0; nf < 4; ++nf)
#pragma unroll
            for (int r = 0; r < 4; ++r) sum += __expf(sc[nf][r] - mn);
        sum += __shfl_xor(sum, 16);
        sum += __shfl_xor(sum, 32);
        l = l * __expf(m - mn) + sum;
        m = mn;
    }
    float rl256 = 256.0f / l;

    // ---- pass 2: recompute scores, p = round(exp*rl*256)/256, PV ----
    f32x4 co[4] = {};
    const float inv256 = 0.00390625f;
    for (int kt = 0; kt < 16; ++kt) {
        __syncthreads();
#pragma unroll
        for (int i = 0; i < 2; ++i) {
            int slot = i * 256 + t;
            __builtin_amdgcn_global_load_lds(
                (const __attribute__((address_space(1))) uint32_t*)(Kp + kt * 4096 + slot * 8),
                (__attribute__((address_space(3))) uint32_t*)(Ks + slot * 8), 16, 0, 0);
            __builtin_amdgcn_global_load_lds(
                (const __attribute__((address_space(1))) uint32_t*)(Vp + kt * 4096 + slot * 8),
                (__attribute__((address_space(3))) uint32_t*)(Vs + slot * 8), 16, 0, 0);
        }
        __syncthreads();
        f32x4 sc[4] = {};
#pragma unroll
        for (int kk = 0; kk < 2; ++kk)
#pragma unroll
            for (int nf = 0; nf < 4; ++nf) {
                f16x8 kf = *(const f16x8*)&Ks[koff[nf][kk]];
                sc[nf] = __builtin_amdgcn_mfma_f32_16x16x32_f16(kf, qf[kk], sc[nf], 0, 0, 0);
            }
        uint32_t pk0[4], pk1[4];
#pragma unroll
        for (int nf = 0; nf < 4; ++nf) {
            float r0 = rintf(__expf(sc[nf][0] - m) * rl256);
            float r1 = rintf(__expf(sc[nf][1] - m) * rl256);
            float r2 = rintf(__expf(sc[nf][2] - m) * rl256);
            float r3 = rintf(__expf(sc[nf][3] - m) * rl256);
            pk0[nf] = __builtin_bit_cast(uint32_t,
                        __builtin_amdgcn_cvt_pkrtz(r0 * inv256, r1 * inv256));
            pk1[nf] = __builtin_bit_cast(uint32_t,
                        __builtin_amdgcn_cvt_pkrtz(r2 * inv256, r3 * inv256));
        }
#pragma unroll
        for (int kk = 0; kk < 2; ++kk) {
            uint4 fw;
            fw.x = pk0[2 * kk];
            fw.y = pk1[2 * kk];
            fw.z = __shfl_xor(pk0[2 * kk + 1], 32);
            fw.w = __shfl_xor(pk1[2 * kk + 1], 32);
            f16x8 pa = __builtin_bit_cast(f16x8, fw);
#pragma unroll
            for (int db = 0; db < 4; ++db) {
                f16x8 vb = *(const f16x8*)&Vs[voff[db][kk]];
                co[db] = __builtin_amdgcn_mfma_f32_16x16x32_f16(pa, vb, co[db], 0, 0, 0);
            }
        }
    }
#pragma unroll
    for (int db = 0; db < 4; ++db)
#pragma unroll
        for (int r = 0; r < 4; ++r) {
            int ss = qt * 64 + w * 16 + lg * 4 + r;
            ctx[((size_t)b * 1024 + ss) * 1024 + h * 64 + db * 16 + lr] = (f16)co[db][r];
        }
}

extern "C" void kernel_launch(void* const* d_in, const int* in_sizes, int n_in,
                              void* d_out, int out_size, void* d_ws, size_t ws_size,
                              hipStream_t stream) {
    const float* x     = (const float*)d_in[0];
    const float* Wqkv  = (const float*)d_in[1];
    const float* bqkv  = (const float*)d_in[2];
    const float* Wout  = (const float*)d_in[3];
    const float* bout  = (const float*)d_in[4];
    const float* W1    = (const float*)d_in[5];
    const float* b1    = (const float*)d_in[6];
    const float* W2    = (const float*)d_in[7];
    const float* b2    = (const float*)d_in[8];
    const float* g1    = (const float*)d_in[9];
    const float* beta1 = (const float*)d_in[10];
    const float* g2    = (const float*)d_in[11];
    const float* beta2 = (const float*)d_in[12];

    char* ws = (char*)d_ws;
    const size_t MB = 1ull << 20;
    f16*  q_h   = (f16*)(ws);             // 16 MB
    f16*  k_h   = (f16*)(ws + 16 * MB);   // 16 MB (swizzled tiled)
    f16*  vt_h  = (f16*)(ws + 32 * MB);   // 16 MB (V^T swizzled tiled)
    f16*  ctx_h = (f16*)(ws + 48 * MB);   // 16 MB
    f16*  h_h   = (f16*)(ws);             // 64 MB, reuses q/k/vt/ctx after attention path
    f16*  xn_h  = (f16*)(ws + 64 * MB);   // 16 MB (xn, later xn2)
    float* x1   = (float*)(ws + 80 * MB); // 32 MB
    f16*  wT    = (f16*)(ws + 112 * MB);  // 8 MB (transposed weight, reused per GEMM)

    // --- attention branch ---
    ln_kernel<<<8192, 256, 0, stream>>>(x, g1, beta1, xn_h);
    transpose_kernel<<<dim3(96, 32), 256, 0, stream>>>(Wqkv, wT, 1024, 3072);
    gemm_kernel<0><<<dim3(64, 24), 256, 0, stream>>>(xn_h, wT, 3072, 1024, bqkv, nullptr, q_h, k_h, vt_h);
    attn_kernel<<<2048, 256, 0, stream>>>(q_h, k_h, vt_h, ctx_h);
    transpose_kernel<<<dim3(32, 32), 256, 0, stream>>>(Wout, wT, 1024, 1024);
    gemm_kernel<1><<<dim3(64, 8), 256, 0, stream>>>(ctx_h, wT, 1024, 1024, bout, x, x1, nullptr, nullptr);
    // --- MLP branch ---
    ln_kernel<<<8192, 256, 0, stream>>>(x1, g2, beta2, xn_h);
    transpose_kernel<<<dim3(128, 32), 256, 0, stream>>>(W1, wT, 1024, 4096);
    gemm_kernel<2><<<dim3(64, 32), 256, 0, stream>>>(xn_h, wT, 4096, 1024, b1, nullptr, h_h, nullptr, nullptr);
    transpose_kernel<<<dim3(32, 128), 256, 0, stream>>>(W2, wT, 4096, 1024);
    gemm_kernel<3><<<dim3(64, 8), 256, 0, stream>>>(h_h, wT, 1024, 4096, b2, x1, d_out, nullptr, nullptr);
}